// Round 7
// baseline (117.316 us; speedup 1.0000x reference)
//
#include <hip/hip_runtime.h>

// Problem constants (B=4, L=2048, C=512, H=8, D=64)
#define CDIM 512
#define LDIM 2048
#define BDIM 4
#define HDIM 8
#define DDIM 64

typedef __attribute__((ext_vector_type(8))) short bf16x8;
typedef __attribute__((ext_vector_type(4))) float f32x4;
typedef __attribute__((ext_vector_type(2))) float f32x2;
typedef __attribute__((ext_vector_type(8))) unsigned short ushort8;

static __device__ __forceinline__ unsigned short f2bf(float f) {
  unsigned u = __float_as_uint(f);
  return (unsigned short)((u + 0x7FFFu + ((u >> 16) & 1u)) >> 16);
}

// ---------------------------------------------------------------------------
// Kernel 0: fp32 -> bf16 convert of qkv_w (786432) + proj_w (262144).
// ---------------------------------------------------------------------------
__global__ __launch_bounds__(256) void convert_kernel(
    const float* __restrict__ qw, const float* __restrict__ pw,
    unsigned short* __restrict__ wb, unsigned short* __restrict__ pwb) {
  const size_t i = ((size_t)blockIdx.x * 256 + threadIdx.x) * 8;
  const float* src; unsigned short* dst; size_t off;
  if (i < 786432) { src = qw; dst = wb;  off = i; }
  else            { src = pw; dst = pwb; off = i - 786432; }
  const float4 a = *(const float4*)(src + off);
  const float4 b = *(const float4*)(src + off + 4);
  ushort8 h;
  h[0] = f2bf(a.x); h[1] = f2bf(a.y); h[2] = f2bf(a.z); h[3] = f2bf(a.w);
  h[4] = f2bf(b.x); h[5] = f2bf(b.y); h[6] = f2bf(b.z); h[7] = f2bf(b.w);
  *(ushort8*)(dst + off) = h;
}

// ---------------------------------------------------------------------------
// Kernel 1: qkv = x @ qkv_w^T + b via bf16 MFMA, fused RoPE epilogue.
// (unchanged from round 6)
// ---------------------------------------------------------------------------
__global__ __launch_bounds__(256) void qkv_gemm_kernel(
    const float* __restrict__ x, const unsigned short* __restrict__ wb,
    const float* __restrict__ bias, const float* __restrict__ cosT,
    const float* __restrict__ sinT, unsigned short* __restrict__ qb,
    unsigned short* __restrict__ kb, unsigned short* __restrict__ vt) {
  __shared__ char As[16384];
  __shared__ char Bs[16384];
  const int t  = threadIdx.x;
  const int w  = t >> 6, lane = t & 63;
  const int lo = lane & 15, hi = lane >> 4;
  const int wm = w >> 1, wn = w & 1;
  const int m0 = blockIdx.y * 128, n0 = blockIdx.x * 128;

  f32x4 acc[4][4];
  #pragma unroll
  for (int mt = 0; mt < 4; ++mt)
    #pragma unroll
    for (int nt = 0; nt < 4; ++nt) acc[mt][nt] = (f32x4){0.f, 0.f, 0.f, 0.f};

  const int srow   = t >> 3;
  const int sch    = (t & 7) ^ (srow & 7);
  const char* Bg = (const char*)wb;

  for (int kt = 0; kt < CDIM; kt += 64) {
    #pragma unroll
    for (int s = 0; s < 4; ++s) {
      const int r = s * 32 + srow;
      const float4 f0 = *(const float4*)(x + (size_t)(m0 + r) * CDIM + kt + sch * 8);
      const float4 f1 = *(const float4*)(x + (size_t)(m0 + r) * CDIM + kt + sch * 8 + 4);
      unsigned u0, u1, u2, u3;
      asm("v_cvt_pk_bf16_f32 %0, %1, %2" : "=v"(u0) : "v"(f0.x), "v"(f0.y));
      asm("v_cvt_pk_bf16_f32 %0, %1, %2" : "=v"(u1) : "v"(f0.z), "v"(f0.w));
      asm("v_cvt_pk_bf16_f32 %0, %1, %2" : "=v"(u2) : "v"(f1.x), "v"(f1.y));
      asm("v_cvt_pk_bf16_f32 %0, %1, %2" : "=v"(u3) : "v"(f1.z), "v"(f1.w));
      uint4 uu; uu.x = u0; uu.y = u1; uu.z = u2; uu.w = u3;
      *(uint4*)(As + s * 4096 + t * 16) = uu;
      __builtin_amdgcn_global_load_lds(
          (const __attribute__((address_space(1))) unsigned int*)
              (Bg + (size_t)(n0 + r) * 1024 + kt * 2 + sch * 16),
          (__attribute__((address_space(3))) unsigned int*)(Bs + s * 4096 + w * 1024),
          16, 0, 0);
    }
    __syncthreads();
    #pragma unroll
    for (int ks = 0; ks < 2; ++ks) {
      bf16x8 af[4], bfr[4];
      #pragma unroll
      for (int mt = 0; mt < 4; ++mt)
        af[mt] = *(const bf16x8*)(As + (wm * 64 + mt * 16 + lo) * 128
                                  + (((ks * 4 + hi) ^ (lo & 7)) << 4));
      #pragma unroll
      for (int nt = 0; nt < 4; ++nt)
        bfr[nt] = *(const bf16x8*)(Bs + (wn * 64 + nt * 16 + lo) * 128
                                   + (((ks * 4 + hi) ^ (lo & 7)) << 4));
      #pragma unroll
      for (int mt = 0; mt < 4; ++mt)
        #pragma unroll
        for (int nt = 0; nt < 4; ++nt)
          acc[mt][nt] = __builtin_amdgcn_mfma_f32_16x16x32_bf16(
              af[mt], bfr[nt], acc[mt][nt], 0, 0, 0);
    }
    __syncthreads();
  }

  const int nbase = n0 + wn * 64;
  const int typ   = nbase >> 9;
  const int hh    = (nbase >> 6) & 7;
  const int bb    = m0 >> 11;
  const int lbase = (m0 & 2047) + wm * 64;

  float bq[4];
  #pragma unroll
  for (int nt = 0; nt < 4; ++nt) bq[nt] = bias[nbase + nt * 16 + lo];
  #pragma unroll
  for (int mt = 0; mt < 4; ++mt)
    #pragma unroll
    for (int nt = 0; nt < 4; ++nt)
      #pragma unroll
      for (int reg = 0; reg < 4; ++reg) acc[mt][nt][reg] += bq[nt];

  if (typ == 2) {
    unsigned short* vbase = vt + (size_t)(bb * HDIM + hh) * DDIM * LDIM;
    #pragma unroll
    for (int mt = 0; mt < 4; ++mt)
      #pragma unroll
      for (int nt = 0; nt < 4; ++nt) {
        const int d = nt * 16 + lo;
        #pragma unroll
        for (int reg = 0; reg < 4; ++reg) {
          const int l = lbase + mt * 16 + hi * 4 + reg;
          vbase[(size_t)d * LDIM + l] = f2bf(acc[mt][nt][reg]);
        }
      }
  } else {
    unsigned short* dstb = (typ ? kb : qb) + (size_t)(bb * HDIM + hh) * LDIM * DDIM;
    #pragma unroll
    for (int mt = 0; mt < 4; ++mt)
      #pragma unroll
      for (int nt = 0; nt < 4; ++nt) {
        const int d   = nt * 16 + lo;
        const float sgn = (nt & 2) ? 1.f : -1.f;
        #pragma unroll
        for (int reg = 0; reg < 4; ++reg) {
          const int l = lbase + mt * 16 + hi * 4 + reg;
          const float c = cosT[l * 64 + d], s = sinT[l * 64 + d];
          const float v = acc[mt][nt][reg] * c + sgn * acc[mt][nt ^ 2][reg] * s;
          dstb[(size_t)l * DDIM + d] = f2bf(v);
        }
      }
  }
}

// ---------------------------------------------------------------------------
// Kernel 2: bf16 MFMA flash attention, 32 q-rows per wave (two 16-row groups
// sharing every kf/vf fragment read -- halves per-q LDS traffic, which round-6
// counters showed is the binding resource at ~49 TB/s). 4 waves x 32 q = 128
// q-rows per block. Dbuf K/V + counted vmcnt(4). Softmax processed per group
// (no max pass, ballot-guarded slow path), P via per-group LDS tile.
// ---------------------------------------------------------------------------
#define CLOG2 0.18033688f          /* 0.125 * log2(e) */

__global__ __launch_bounds__(256) void attn_kernel(
    unsigned short* __restrict__ qb, const unsigned short* __restrict__ kb,
    const unsigned short* __restrict__ vt) {
  __shared__ char Ks[2][8192];
  __shared__ char Vs[2][8192];
  __shared__ char Pw[16384];
  const int t    = threadIdx.x;
  const int w    = t >> 6, lane = t & 63;
  const int lo   = lane & 15, hi = lane >> 4;
  const int bh   = blockIdx.y;
  const int q0   = blockIdx.x * 128 + w * 32;

  const char* Kb = (const char*)kb + (size_t)bh * (LDIM * DDIM * 2);
  const char* Vb = (const char*)vt + (size_t)bh * (LDIM * DDIM * 2);
  unsigned short* Qb = qb + (size_t)bh * (LDIM * DDIM);

  // Q fragments, two groups: lane holds Q[q0+g*16+lo][kd*32 + hi*8 .. +7]
  bf16x8 qf[2][2];
  #pragma unroll
  for (int g = 0; g < 2; ++g)
    #pragma unroll
    for (int kd = 0; kd < 2; ++kd)
      qf[g][kd] = *(const bf16x8*)((const char*)(Qb + (size_t)(q0 + g * 16 + lo) * DDIM)
                                   + kd * 64 + hi * 16);

  f32x4 o[2][4];
  float mrun[2] = {0.f, 0.f}, mc[2] = {0.f, 0.f}, lpart[2] = {0.f, 0.f};
  #pragma unroll
  for (int g = 0; g < 2; ++g)
    #pragma unroll
    for (int r = 0; r < 4; ++r) o[g][r] = (f32x4){0.f, 0.f, 0.f, 0.f};

  const int rloc = lane >> 3;
  const int sw   = ((lane & 7) ^ rloc) << 4;
  char* Pwb = Pw + w * 4096;

  auto stage = [&](int tile, int buf) {
    #pragma unroll
    for (int s = 0; s < 2; ++s) {
      const int r = w * 16 + s * 8 + rloc;
      __builtin_amdgcn_global_load_lds(
          (const __attribute__((address_space(1))) unsigned int*)
              (Kb + (size_t)(tile * 64 + r) * 128 + sw),
          (__attribute__((address_space(3))) unsigned int*)(&Ks[buf][(w * 2 + s) * 1024]),
          16, 0, 0);
      __builtin_amdgcn_global_load_lds(
          (const __attribute__((address_space(1))) unsigned int*)
              (Vb + (size_t)r * (LDIM * 2) + tile * 128 + sw),
          (__attribute__((address_space(3))) unsigned int*)(&Vs[buf][(w * 2 + s) * 1024]),
          16, 0, 0);
    }
  };

  stage(0, 0);   // prologue

  for (int kt = 0; kt < 32; ++kt) {
    const int cur = kt & 1;
    const int nk  = kt < 31 ? kt + 1 : 31;   // clamp: last prefetch is dummy
    stage(nk, cur ^ 1);
    asm volatile("s_waitcnt vmcnt(4)");      // current tile landed; next flies
    __builtin_amdgcn_s_barrier();
    __builtin_amdgcn_sched_barrier(0);

    // ---- S^T = K Q, both q-groups share each kf read ----
    f32x4 sv[2][4];
    __builtin_amdgcn_s_setprio(1);
    #pragma unroll
    for (int nt = 0; nt < 4; ++nt) {
      sv[0][nt] = (f32x4){0.f, 0.f, 0.f, 0.f};
      sv[1][nt] = (f32x4){0.f, 0.f, 0.f, 0.f};
      const int key = nt * 16 + lo;
      #pragma unroll
      for (int kd = 0; kd < 2; ++kd) {
        const bf16x8 kf = *(const bf16x8*)(&Ks[cur][0] + key * 128
                            + (((kd * 4 + hi) ^ (key & 7)) << 4));
        sv[0][nt] = __builtin_amdgcn_mfma_f32_16x16x32_bf16(kf, qf[0][kd], sv[0][nt], 0, 0, 0);
        sv[1][nt] = __builtin_amdgcn_mfma_f32_16x16x32_bf16(kf, qf[1][kd], sv[1][nt], 0, 0, 0);
      }
    }
    __builtin_amdgcn_s_setprio(0);

    // ---- softmax per group: no max pass; pk_fma + raw v_exp_f32 ----
    #pragma unroll
    for (int g = 0; g < 2; ++g) {
      const float* sflat = (const float*)sv[g];
      const f32x2 cc2 = {CLOG2, CLOG2};
      const f32x2 mm2 = {-mc[g], -mc[g]};
      float pv[16];
      float ps = 0.f;
      #pragma unroll
      for (int i = 0; i < 8; ++i) {
        f32x2 a; a[0] = sflat[2*i]; a[1] = sflat[2*i+1];
        f32x2 xr;
        asm("v_pk_fma_f32 %0, %1, %2, %3" : "=v"(xr) : "v"(a), "v"(cc2), "v"(mm2));
        float p0, p1;
        asm("v_exp_f32 %0, %1" : "=v"(p0) : "v"(xr[0]));
        asm("v_exp_f32 %0, %1" : "=v"(p1) : "v"(xr[1]));
        pv[2*i] = p0; pv[2*i+1] = p1;
        ps += p0; ps += p1;
      }

      if (__builtin_expect((bool)__ballot(ps > 65536.f), 0)) {
        // slow path: true row max, rescale history, recompute p (cold, exact)
        float mx = -1e30f;
        #pragma unroll
        for (int i = 0; i < 16; ++i) mx = fmaxf(mx, sflat[i]);
        mx = fmaxf(mx, __shfl_xor(mx, 16));
        mx = fmaxf(mx, __shfl_xor(mx, 32));
        const float newm = fmaxf(mrun[g], mx);
        const float al   = exp2f((mrun[g] - newm) * CLOG2);
        lpart[g] *= al;
        #pragma unroll
        for (int r = 0; r < 4; ++r) {
          const float aq = __shfl(al, (hi << 2) + r);
          #pragma unroll
          for (int dt = 0; dt < 4; ++dt) o[g][dt][r] *= aq;
        }
        mrun[g] = newm;
        mc[g]   = mrun[g] * CLOG2;
        ps = 0.f;
        #pragma unroll
        for (int i = 0; i < 16; ++i) {
          const float p = exp2f(fmaf(sflat[i], CLOG2, -mc[g]));
          pv[i] = p;
          ps += p;
        }
      }
      lpart[g] += ps;

      // pack P (RNE) and store 4x b64 into this group's half of the P tile
      #pragma unroll
      for (int nt = 0; nt < 4; ++nt) {
        unsigned w0, w1;
        asm("v_cvt_pk_bf16_f32 %0, %1, %2"
            : "=v"(w0) : "v"(pv[nt*4+0]), "v"(pv[nt*4+1]));
        asm("v_cvt_pk_bf16_f32 %0, %1, %2"
            : "=v"(w1) : "v"(pv[nt*4+2]), "v"(pv[nt*4+3]));
        uint2 d2; d2.x = w0; d2.y = w1;
        *(uint2*)(Pwb + g * 2048 + lo * 128
                  + ((nt * 32 + hi * 8) ^ ((lo & 7) << 4))) = d2;
      }
    }

    // ---- O += P V, both groups share each vf read ----
    __builtin_amdgcn_s_setprio(1);
    #pragma unroll
    for (int ks = 0; ks < 2; ++ks) {
      const bf16x8 pf0 = *(const bf16x8*)(Pwb + lo * 128
                           + (((ks * 4 + hi) ^ (lo & 7)) << 4));
      const bf16x8 pf1 = *(const bf16x8*)(Pwb + 2048 + lo * 128
                           + (((ks * 4 + hi) ^ (lo & 7)) << 4));
      #pragma unroll
      for (int dt = 0; dt < 4; ++dt) {
        const int d = dt * 16 + lo;
        const bf16x8 vf = *(const bf16x8*)(&Vs[cur][0] + d * 128
                            + (((ks * 4 + hi) ^ (d & 7)) << 4));
        o[0][dt] = __builtin_amdgcn_mfma_f32_16x16x32_bf16(pf0, vf, o[0][dt], 0, 0, 0);
        o[1][dt] = __builtin_amdgcn_mfma_f32_16x16x32_bf16(pf1, vf, o[1][dt], 0, 0, 0);
      }
    }
    __builtin_amdgcn_s_setprio(0);

    __builtin_amdgcn_sched_barrier(0);
    __builtin_amdgcn_s_barrier();   // all reads of buf[cur] done before reuse
  }

  // ---- final row-sum reduction + normalize + bf16 output over qb ----
  #pragma unroll
  for (int g = 0; g < 2; ++g) {
    float rsum = lpart[g];
    rsum += __shfl_xor(rsum, 16);
    rsum += __shfl_xor(rsum, 32);
    #pragma unroll
    for (int r = 0; r < 4; ++r) {
      const float lr  = __shfl(rsum, (hi << 2) + r);
      const float inv = 1.f / lr;
      const int q = q0 + g * 16 + hi * 4 + r;
      #pragma unroll
      for (int dt = 0; dt < 4; ++dt)
        Qb[(size_t)q * DDIM + dt * 16 + lo] = f2bf(o[g][dt][r] * inv);
    }
  }
}

// ---------------------------------------------------------------------------
// Kernel 3: out = attn_out @ proj_w^T + b via bf16 MFMA (unchanged).
// ---------------------------------------------------------------------------
__global__ __launch_bounds__(256) void proj_gemm_kernel(
    const unsigned short* __restrict__ ab, const unsigned short* __restrict__ pwb,
    const float* __restrict__ bias, float* __restrict__ out) {
  __shared__ char As[16384];
  __shared__ char Bs[16384];
  const int t  = threadIdx.x;
  const int w  = t >> 6, lane = t & 63;
  const int lo = lane & 15, hi = lane >> 4;
  const int wm = w >> 1, wn = w & 1;
  const int m0 = blockIdx.y * 128, n0 = blockIdx.x * 128;

  f32x4 acc[4][4];
  #pragma unroll
  for (int mt = 0; mt < 4; ++mt)
    #pragma unroll
    for (int nt = 0; nt < 4; ++nt) acc[mt][nt] = (f32x4){0.f, 0.f, 0.f, 0.f};

  const int srow   = t >> 3;
  const int schunk = ((t & 7) ^ (srow & 7)) << 4;
  const char* Ag = (const char*)ab;
  const char* Bg = (const char*)pwb;

  for (int kt = 0; kt < CDIM; kt += 64) {
    const int hh = kt >> 6;
    #pragma unroll
    for (int s = 0; s < 4; ++s) {
      const int r = s * 32 + srow;
      const int m = m0 + r;
      const int bb = m >> 11, l = m & 2047;
      __builtin_amdgcn_global_load_lds(
          (const __attribute__((address_space(1))) unsigned int*)
              (Ag + ((size_t)(bb * HDIM + hh) * LDIM + l) * 128 + schunk),
          (__attribute__((address_space(3))) unsigned int*)(As + s * 4096 + w * 1024),
          16, 0, 0);
      __builtin_amdgcn_global_load_lds(
          (const __attribute__((address_space(1))) unsigned int*)
              (Bg + (size_t)(n0 + r) * 1024 + kt * 2 + schunk),
          (__attribute__((address_space(3))) unsigned int*)(Bs + s * 4096 + w * 1024),
          16, 0, 0);
    }
    __syncthreads();
    #pragma unroll
    for (int ks = 0; ks < 2; ++ks) {
      bf16x8 af[4], bfr[4];
      #pragma unroll
      for (int mt = 0; mt < 4; ++mt)
        af[mt] = *(const bf16x8*)(As + (wm * 64 + mt * 16 + lo) * 128
                                  + (((ks * 4 + hi) ^ (lo & 7)) << 4));
      #pragma unroll
      for (int nt = 0; nt < 4; ++nt)
        bfr[nt] = *(const bf16x8*)(Bs + (wn * 64 + nt * 16 + lo) * 128
                                   + (((ks * 4 + hi) ^ (lo & 7)) << 4));
      #pragma unroll
      for (int mt = 0; mt < 4; ++mt)
        #pragma unroll
        for (int nt = 0; nt < 4; ++nt)
          acc[mt][nt] = __builtin_amdgcn_mfma_f32_16x16x32_bf16(
              af[mt], bfr[nt], acc[mt][nt], 0, 0, 0);
    }
    __syncthreads();
  }

  const int nn = n0 + wn * 64;
  float bp[4];
  #pragma unroll
  for (int nt = 0; nt < 4; ++nt) bp[nt] = bias[nn + nt * 16 + lo];
  #pragma unroll
  for (int mt = 0; mt < 4; ++mt)
    #pragma unroll
    for (int nt = 0; nt < 4; ++nt)
      #pragma unroll
      for (int reg = 0; reg < 4; ++reg) {
        const int m = m0 + wm * 64 + mt * 16 + hi * 4 + reg;
        out[(size_t)m * CDIM + nn + nt * 16 + lo] = acc[mt][nt][reg] + bp[nt];
      }
}

// ---------------------------------------------------------------------------
extern "C" void kernel_launch(void* const* d_in, const int* in_sizes, int n_in,
                              void* d_out, int out_size, void* d_ws, size_t ws_size,
                              hipStream_t stream) {
  const float* x      = (const float*)d_in[0];
  const float* qkv_w  = (const float*)d_in[1];
  const float* qkv_b  = (const float*)d_in[2];
  const float* proj_w = (const float*)d_in[3];
  const float* proj_b = (const float*)d_in[4];
  const float* cosT   = (const float*)d_in[5];
  const float* sinT   = (const float*)d_in[6];
  float* out = (float*)d_out;

  // ws layout (u16): qb 8MB | kb 8MB | vt 8MB | wb 1.5MB | pwb 0.5MB
  unsigned short* qb  = (unsigned short*)d_ws;
  unsigned short* kb  = qb + (size_t)BDIM * HDIM * LDIM * DDIM;
  unsigned short* vt  = kb + (size_t)BDIM * HDIM * LDIM * DDIM;
  unsigned short* wb  = vt + (size_t)BDIM * HDIM * LDIM * DDIM;
  unsigned short* pwb = wb + (size_t)3 * CDIM * CDIM;

  // 0) fp32 -> bf16 weight conversions (x is converted inside qkv staging)
  convert_kernel<<<dim3(512), 256, 0, stream>>>(qkv_w, proj_w, wb, pwb);
  // 1) QKV GEMM (bf16 MFMA, fp32-x fused convert) + fused RoPE + scatter
  qkv_gemm_kernel<<<dim3(12, 64), 256, 0, stream>>>(x, wb, qkv_b, cosT, sinT,
                                                    qb, kb, vt);
  // 2) bf16 MFMA flash attention (4 waves x 32 q-rows, dbuf, counted vmcnt)
  attn_kernel<<<dim3(16, 32), 256, 0, stream>>>(qb, kb, vt);
  // 3) output projection (bf16 MFMA, fp32 out)
  proj_gemm_kernel<<<dim3(4, 64), 256, 0, stream>>>(qb, pwb, proj_b, out);
}

// Round 8
// 107.709 us; speedup vs baseline: 1.0892x; 1.0892x over previous
//
#include <hip/hip_runtime.h>

// Problem constants (B=4, L=2048, C=512, H=8, D=64)
#define CDIM 512
#define LDIM 2048
#define BDIM 4
#define HDIM 8
#define DDIM 64

typedef __attribute__((ext_vector_type(8))) short bf16x8;
typedef __attribute__((ext_vector_type(4))) float f32x4;
typedef __attribute__((ext_vector_type(2))) float f32x2;
typedef __attribute__((ext_vector_type(8))) unsigned short ushort8;

static __device__ __forceinline__ unsigned short f2bf(float f) {
  unsigned u = __float_as_uint(f);
  return (unsigned short)((u + 0x7FFFu + ((u >> 16) & 1u)) >> 16);
}

// ---------------------------------------------------------------------------
// Kernel 0: fp32 -> bf16 convert of qkv_w (786432) + proj_w (262144).
// ---------------------------------------------------------------------------
__global__ __launch_bounds__(256) void convert_kernel(
    const float* __restrict__ qw, const float* __restrict__ pw,
    unsigned short* __restrict__ wb, unsigned short* __restrict__ pwb) {
  const size_t i = ((size_t)blockIdx.x * 256 + threadIdx.x) * 8;
  const float* src; unsigned short* dst; size_t off;
  if (i < 786432) { src = qw; dst = wb;  off = i; }
  else            { src = pw; dst = pwb; off = i - 786432; }
  const float4 a = *(const float4*)(src + off);
  const float4 b = *(const float4*)(src + off + 4);
  ushort8 h;
  h[0] = f2bf(a.x); h[1] = f2bf(a.y); h[2] = f2bf(a.z); h[3] = f2bf(a.w);
  h[4] = f2bf(b.x); h[5] = f2bf(b.y); h[6] = f2bf(b.z); h[7] = f2bf(b.w);
  *(ushort8*)(dst + off) = h;
}

// ---------------------------------------------------------------------------
// Kernel 1: qkv = x @ qkv_w^T + b via bf16 MFMA, fused RoPE epilogue.
// (unchanged from round 6/7)
// ---------------------------------------------------------------------------
__global__ __launch_bounds__(256) void qkv_gemm_kernel(
    const float* __restrict__ x, const unsigned short* __restrict__ wb,
    const float* __restrict__ bias, const float* __restrict__ cosT,
    const float* __restrict__ sinT, unsigned short* __restrict__ qb,
    unsigned short* __restrict__ kb, unsigned short* __restrict__ vt) {
  __shared__ char As[16384];
  __shared__ char Bs[16384];
  const int t  = threadIdx.x;
  const int w  = t >> 6, lane = t & 63;
  const int lo = lane & 15, hi = lane >> 4;
  const int wm = w >> 1, wn = w & 1;
  const int m0 = blockIdx.y * 128, n0 = blockIdx.x * 128;

  f32x4 acc[4][4];
  #pragma unroll
  for (int mt = 0; mt < 4; ++mt)
    #pragma unroll
    for (int nt = 0; nt < 4; ++nt) acc[mt][nt] = (f32x4){0.f, 0.f, 0.f, 0.f};

  const int srow   = t >> 3;
  const int sch    = (t & 7) ^ (srow & 7);
  const char* Bg = (const char*)wb;

  for (int kt = 0; kt < CDIM; kt += 64) {
    #pragma unroll
    for (int s = 0; s < 4; ++s) {
      const int r = s * 32 + srow;
      const float4 f0 = *(const float4*)(x + (size_t)(m0 + r) * CDIM + kt + sch * 8);
      const float4 f1 = *(const float4*)(x + (size_t)(m0 + r) * CDIM + kt + sch * 8 + 4);
      unsigned u0, u1, u2, u3;
      asm("v_cvt_pk_bf16_f32 %0, %1, %2" : "=v"(u0) : "v"(f0.x), "v"(f0.y));
      asm("v_cvt_pk_bf16_f32 %0, %1, %2" : "=v"(u1) : "v"(f0.z), "v"(f0.w));
      asm("v_cvt_pk_bf16_f32 %0, %1, %2" : "=v"(u2) : "v"(f1.x), "v"(f1.y));
      asm("v_cvt_pk_bf16_f32 %0, %1, %2" : "=v"(u3) : "v"(f1.z), "v"(f1.w));
      uint4 uu; uu.x = u0; uu.y = u1; uu.z = u2; uu.w = u3;
      *(uint4*)(As + s * 4096 + t * 16) = uu;
      __builtin_amdgcn_global_load_lds(
          (const __attribute__((address_space(1))) unsigned int*)
              (Bg + (size_t)(n0 + r) * 1024 + kt * 2 + sch * 16),
          (__attribute__((address_space(3))) unsigned int*)(Bs + s * 4096 + w * 1024),
          16, 0, 0);
    }
    __syncthreads();
    #pragma unroll
    for (int ks = 0; ks < 2; ++ks) {
      bf16x8 af[4], bfr[4];
      #pragma unroll
      for (int mt = 0; mt < 4; ++mt)
        af[mt] = *(const bf16x8*)(As + (wm * 64 + mt * 16 + lo) * 128
                                  + (((ks * 4 + hi) ^ (lo & 7)) << 4));
      #pragma unroll
      for (int nt = 0; nt < 4; ++nt)
        bfr[nt] = *(const bf16x8*)(Bs + (wn * 64 + nt * 16 + lo) * 128
                                   + (((ks * 4 + hi) ^ (lo & 7)) << 4));
      #pragma unroll
      for (int mt = 0; mt < 4; ++mt)
        #pragma unroll
        for (int nt = 0; nt < 4; ++nt)
          acc[mt][nt] = __builtin_amdgcn_mfma_f32_16x16x32_bf16(
              af[mt], bfr[nt], acc[mt][nt], 0, 0, 0);
    }
    __syncthreads();
  }

  const int nbase = n0 + wn * 64;
  const int typ   = nbase >> 9;
  const int hh    = (nbase >> 6) & 7;
  const int bb    = m0 >> 11;
  const int lbase = (m0 & 2047) + wm * 64;

  float bq[4];
  #pragma unroll
  for (int nt = 0; nt < 4; ++nt) bq[nt] = bias[nbase + nt * 16 + lo];
  #pragma unroll
  for (int mt = 0; mt < 4; ++mt)
    #pragma unroll
    for (int nt = 0; nt < 4; ++nt)
      #pragma unroll
      for (int reg = 0; reg < 4; ++reg) acc[mt][nt][reg] += bq[nt];

  if (typ == 2) {
    unsigned short* vbase = vt + (size_t)(bb * HDIM + hh) * DDIM * LDIM;
    #pragma unroll
    for (int mt = 0; mt < 4; ++mt)
      #pragma unroll
      for (int nt = 0; nt < 4; ++nt) {
        const int d = nt * 16 + lo;
        #pragma unroll
        for (int reg = 0; reg < 4; ++reg) {
          const int l = lbase + mt * 16 + hi * 4 + reg;
          vbase[(size_t)d * LDIM + l] = f2bf(acc[mt][nt][reg]);
        }
      }
  } else {
    unsigned short* dstb = (typ ? kb : qb) + (size_t)(bb * HDIM + hh) * LDIM * DDIM;
    #pragma unroll
    for (int mt = 0; mt < 4; ++mt)
      #pragma unroll
      for (int nt = 0; nt < 4; ++nt) {
        const int d   = nt * 16 + lo;
        const float sgn = (nt & 2) ? 1.f : -1.f;
        #pragma unroll
        for (int reg = 0; reg < 4; ++reg) {
          const int l = lbase + mt * 16 + hi * 4 + reg;
          const float c = cosT[l * 64 + d], s = sinT[l * 64 + d];
          const float v = acc[mt][nt][reg] * c + sgn * acc[mt][nt ^ 2][reg] * s;
          dstb[(size_t)l * DDIM + d] = f2bf(v);
        }
      }
  }
}

// ---------------------------------------------------------------------------
// Kernel 2: bf16 MFMA flash attention, KV-split.
// Block = 8 waves = 4 q-groups x 2 KV-halves; wave owns 32 q-rows and one
// 1024-key half (32 tiles of 32 keys). 4096 waves total -> 16 waves/CU
// (fixes round-7 TLP collapse) while keeping the 32q/wave LDS amortization.
// K tile [32k][128B], V tile [64d][64B], per-half dbuf, counted vmcnt(2).
// Softmax: no-max fast path + ballot slow path (as rounds 5-7). Halves merge
// O/l/m partials through LDS (aliased over staging after vmcnt(0) drain).
// ---------------------------------------------------------------------------
#define CLOG2 0.18033688f          /* 0.125 * log2(e) */

__global__ __launch_bounds__(512, 4) void attn_kernel(
    unsigned short* __restrict__ qb, const unsigned short* __restrict__ kb,
    const unsigned short* __restrict__ vt) {
  __shared__ char Lds[65536];
  // [0,16K)  K staging: (half*2+buf)*4096
  // [16K,32K) V staging: 16384 + (half*2+buf)*4096
  // [32K,64K) P tiles:   32768 + w*4096 (+ g*2048)
  // epilogue alias: O_b at wq*8192 in [0,32K); l/m at 32768 + wq*256
  const int t    = threadIdx.x;
  const int w    = t >> 6, lane = t & 63;
  const int lo   = lane & 15, hi = lane >> 4;
  const int wq   = w & 3, half = w >> 2;
  const int bh   = blockIdx.y;
  const int q0   = blockIdx.x * 128 + wq * 32;
  const int kb0  = half * 1024;                 // key offset of this half

  const char* Kb = (const char*)kb + (size_t)bh * (LDIM * DDIM * 2);
  const char* Vb = (const char*)vt + (size_t)bh * (LDIM * DDIM * 2);
  unsigned short* Qb = qb + (size_t)bh * (LDIM * DDIM);

  // Q fragments (B-operand of mfma(K, Q)), 2 groups of 16 q-rows
  bf16x8 qf[2][2];
  #pragma unroll
  for (int g = 0; g < 2; ++g)
    #pragma unroll
    for (int kd = 0; kd < 2; ++kd)
      qf[g][kd] = *(const bf16x8*)((const char*)(Qb + (size_t)(q0 + g * 16 + lo) * DDIM)
                                   + kd * 64 + hi * 16);

  f32x4 o[2][4];
  float mrun[2] = {0.f, 0.f}, mc[2] = {0.f, 0.f}, lpart[2] = {0.f, 0.f};
  #pragma unroll
  for (int g = 0; g < 2; ++g)
    #pragma unroll
    for (int r = 0; r < 4; ++r) o[g][r] = (f32x4){0.f, 0.f, 0.f, 0.f};

  // staging lane roles (pre-swizzled global source, linear LDS dest)
  const int krow = wq * 8 + (lane >> 3);        // key row 0..31
  const int kch  = ((lane & 7) ^ (krow & 7)) << 4;
  const int vrow = wq * 16 + (lane >> 2);       // d row 0..63
  const int vch  = ((lane & 3) ^ (vrow & 3)) << 4;

  auto stage = [&](int tile, int buf) {
    __builtin_amdgcn_global_load_lds(
        (const __attribute__((address_space(1))) unsigned int*)
            (Kb + (size_t)(kb0 + tile * 32 + krow) * 128 + kch),
        (__attribute__((address_space(3))) unsigned int*)
            (Lds + (half * 2 + buf) * 4096 + wq * 1024),
        16, 0, 0);
    __builtin_amdgcn_global_load_lds(
        (const __attribute__((address_space(1))) unsigned int*)
            (Vb + (size_t)vrow * (LDIM * 2) + (size_t)(kb0 + tile * 32) * 2 + vch),
        (__attribute__((address_space(3))) unsigned int*)
            (Lds + 16384 + (half * 2 + buf) * 4096 + wq * 1024),
        16, 0, 0);
  };

  stage(0, 0);   // prologue

  char* Pwb = Lds + 32768 + w * 4096;

  for (int kt = 0; kt < 32; ++kt) {
    const int cur = kt & 1;
    const int nk  = kt < 31 ? kt + 1 : 31;      // last prefetch is a dummy
    stage(nk, cur ^ 1);
    asm volatile("s_waitcnt vmcnt(2)");         // current tile landed
    __builtin_amdgcn_s_barrier();
    __builtin_amdgcn_sched_barrier(0);

    const char* Kl = Lds + (half * 2 + cur) * 4096;
    const char* Vl = Lds + 16384 + (half * 2 + cur) * 4096;

    // ---- S^T = K Q : lane gets 8 raw scores per group for q-row lo ----
    f32x4 sv[2][2];
    __builtin_amdgcn_s_setprio(1);
    #pragma unroll
    for (int nt = 0; nt < 2; ++nt) {
      sv[0][nt] = (f32x4){0.f, 0.f, 0.f, 0.f};
      sv[1][nt] = (f32x4){0.f, 0.f, 0.f, 0.f};
      const int key = nt * 16 + lo;
      #pragma unroll
      for (int kd = 0; kd < 2; ++kd) {
        const bf16x8 kf = *(const bf16x8*)(Kl + key * 128
                            + (((kd * 4 + hi) ^ (lo & 7)) << 4));
        sv[0][nt] = __builtin_amdgcn_mfma_f32_16x16x32_bf16(kf, qf[0][kd], sv[0][nt], 0, 0, 0);
        sv[1][nt] = __builtin_amdgcn_mfma_f32_16x16x32_bf16(kf, qf[1][kd], sv[1][nt], 0, 0, 0);
      }
    }
    __builtin_amdgcn_s_setprio(0);

    // ---- softmax per group: no max pass; pk_fma + raw v_exp_f32 ----
    #pragma unroll
    for (int g = 0; g < 2; ++g) {
      const float* sflat = (const float*)sv[g];
      const f32x2 cc2 = {CLOG2, CLOG2};
      const f32x2 mm2 = {-mc[g], -mc[g]};
      float pv[8];
      float ps = 0.f;
      #pragma unroll
      for (int i = 0; i < 4; ++i) {
        f32x2 a; a[0] = sflat[2*i]; a[1] = sflat[2*i+1];
        f32x2 xr;
        asm("v_pk_fma_f32 %0, %1, %2, %3" : "=v"(xr) : "v"(a), "v"(cc2), "v"(mm2));
        float p0, p1;
        asm("v_exp_f32 %0, %1" : "=v"(p0) : "v"(xr[0]));
        asm("v_exp_f32 %0, %1" : "=v"(p1) : "v"(xr[1]));
        pv[2*i] = p0; pv[2*i+1] = p1;
        ps += p0; ps += p1;
      }

      if (__builtin_expect((bool)__ballot(ps > 65536.f), 0)) {
        // slow path: true row max, rescale history, recompute p (cold, exact)
        float mx = -1e30f;
        #pragma unroll
        for (int i = 0; i < 8; ++i) mx = fmaxf(mx, sflat[i]);
        mx = fmaxf(mx, __shfl_xor(mx, 16));
        mx = fmaxf(mx, __shfl_xor(mx, 32));
        const float newm = fmaxf(mrun[g], mx);
        const float al   = exp2f((mrun[g] - newm) * CLOG2);
        lpart[g] *= al;
        #pragma unroll
        for (int r = 0; r < 4; ++r) {
          const float aq = __shfl(al, (hi << 2) + r);
          #pragma unroll
          for (int dt = 0; dt < 4; ++dt) o[g][dt][r] *= aq;
        }
        mrun[g] = newm;
        mc[g]   = newm * CLOG2;
        ps = 0.f;
        #pragma unroll
        for (int i = 0; i < 8; ++i) {
          const float p = exp2f(fmaf(sflat[i], CLOG2, -mc[g]));
          pv[i] = p;
          ps += p;
        }
      }
      lpart[g] += ps;

      // pack P (RNE) and store 2x b64 into this group's P tile
      #pragma unroll
      for (int nt = 0; nt < 2; ++nt) {
        unsigned w0, w1;
        asm("v_cvt_pk_bf16_f32 %0, %1, %2"
            : "=v"(w0) : "v"(pv[nt*4+0]), "v"(pv[nt*4+1]));
        asm("v_cvt_pk_bf16_f32 %0, %1, %2"
            : "=v"(w1) : "v"(pv[nt*4+2]), "v"(pv[nt*4+3]));
        uint2 d2; d2.x = w0; d2.y = w1;
        *(uint2*)(Pwb + g * 2048 + lo * 128
                  + ((nt * 32 + hi * 8) ^ ((lo & 7) << 4))) = d2;
      }
    }

    // ---- O += P V (single K=32 step per tile) ----
    __builtin_amdgcn_s_setprio(1);
    {
      const bf16x8 pf0 = *(const bf16x8*)(Pwb + lo * 128
                           + ((hi ^ (lo & 7)) << 4));
      const bf16x8 pf1 = *(const bf16x8*)(Pwb + 2048 + lo * 128
                           + ((hi ^ (lo & 7)) << 4));
      #pragma unroll
      for (int dt = 0; dt < 4; ++dt) {
        const int d = dt * 16 + lo;
        const bf16x8 vf = *(const bf16x8*)(Vl + d * 64 + ((hi ^ (lo & 3)) << 4));
        o[0][dt] = __builtin_amdgcn_mfma_f32_16x16x32_bf16(pf0, vf, o[0][dt], 0, 0, 0);
        o[1][dt] = __builtin_amdgcn_mfma_f32_16x16x32_bf16(pf1, vf, o[1][dt], 0, 0, 0);
      }
    }
    __builtin_amdgcn_s_setprio(0);

    __builtin_amdgcn_sched_barrier(0);
    __builtin_amdgcn_s_barrier();   // all reads of buf[cur] done before reuse
  }

  // ---- epilogue: drain dummy prefetch, merge halves through LDS ----
  asm volatile("s_waitcnt vmcnt(0)");
  __syncthreads();

  float rs[2];
  #pragma unroll
  for (int g = 0; g < 2; ++g) {
    rs[g] = lpart[g];
    rs[g] += __shfl_xor(rs[g], 16);
    rs[g] += __shfl_xor(rs[g], 32);
  }

  if (half == 1) {
    #pragma unroll
    for (int g = 0; g < 2; ++g) {
      #pragma unroll
      for (int dt = 0; dt < 4; ++dt)
        #pragma unroll
        for (int r = 0; r < 4; ++r)
          *(float*)(Lds + wq * 8192
                    + ((g * 16 + hi * 4 + r) * 64 + dt * 16 + lo) * 4) = o[g][dt][r];
      if (hi == 0) {
        *(float*)(Lds + 32768 + wq * 256 + g * 64 + lo * 4)       = rs[g];
        *(float*)(Lds + 32768 + wq * 256 + 128 + g * 64 + lo * 4) = mrun[g];
      }
    }
  }
  __syncthreads();
  if (half == 0) {
    #pragma unroll
    for (int g = 0; g < 2; ++g)
      #pragma unroll
      for (int r = 0; r < 4; ++r) {
        const int qrow = hi * 4 + r;
        const float m_a = __shfl(mrun[g], qrow);
        const float l_a = __shfl(rs[g], qrow);
        const float l_b = *(const float*)(Lds + 32768 + wq * 256 + g * 64 + qrow * 4);
        const float m_b = *(const float*)(Lds + 32768 + wq * 256 + 128 + g * 64 + qrow * 4);
        const float m  = fmaxf(m_a, m_b);
        const float aa = exp2f((m_a - m) * CLOG2);
        const float ab = exp2f((m_b - m) * CLOG2);
        const float inv = 1.f / (l_a * aa + l_b * ab);
        const int q = q0 + g * 16 + qrow;
        #pragma unroll
        for (int dt = 0; dt < 4; ++dt) {
          const float ob = *(const float*)(Lds + wq * 8192
                            + ((g * 16 + qrow) * 64 + dt * 16 + lo) * 4);
          Qb[(size_t)q * DDIM + dt * 16 + lo] =
              f2bf((o[g][dt][r] * aa + ob * ab) * inv);
        }
      }
  }
}

// ---------------------------------------------------------------------------
// Kernel 3: out = attn_out @ proj_w^T + b via bf16 MFMA (unchanged).
// ---------------------------------------------------------------------------
__global__ __launch_bounds__(256) void proj_gemm_kernel(
    const unsigned short* __restrict__ ab, const unsigned short* __restrict__ pwb,
    const float* __restrict__ bias, float* __restrict__ out) {
  __shared__ char As[16384];
  __shared__ char Bs[16384];
  const int t  = threadIdx.x;
  const int w  = t >> 6, lane = t & 63;
  const int lo = lane & 15, hi = lane >> 4;
  const int wm = w >> 1, wn = w & 1;
  const int m0 = blockIdx.y * 128, n0 = blockIdx.x * 128;

  f32x4 acc[4][4];
  #pragma unroll
  for (int mt = 0; mt < 4; ++mt)
    #pragma unroll
    for (int nt = 0; nt < 4; ++nt) acc[mt][nt] = (f32x4){0.f, 0.f, 0.f, 0.f};

  const int srow   = t >> 3;
  const int schunk = ((t & 7) ^ (srow & 7)) << 4;
  const char* Ag = (const char*)ab;
  const char* Bg = (const char*)pwb;

  for (int kt = 0; kt < CDIM; kt += 64) {
    const int hh = kt >> 6;
    #pragma unroll
    for (int s = 0; s < 4; ++s) {
      const int r = s * 32 + srow;
      const int m = m0 + r;
      const int bb = m >> 11, l = m & 2047;
      __builtin_amdgcn_global_load_lds(
          (const __attribute__((address_space(1))) unsigned int*)
              (Ag + ((size_t)(bb * HDIM + hh) * LDIM + l) * 128 + schunk),
          (__attribute__((address_space(3))) unsigned int*)(As + s * 4096 + w * 1024),
          16, 0, 0);
      __builtin_amdgcn_global_load_lds(
          (const __attribute__((address_space(1))) unsigned int*)
              (Bg + (size_t)(n0 + r) * 1024 + kt * 2 + schunk),
          (__attribute__((address_space(3))) unsigned int*)(Bs + s * 4096 + w * 1024),
          16, 0, 0);
    }
    __syncthreads();
    #pragma unroll
    for (int ks = 0; ks < 2; ++ks) {
      bf16x8 af[4], bfr[4];
      #pragma unroll
      for (int mt = 0; mt < 4; ++mt)
        af[mt] = *(const bf16x8*)(As + (wm * 64 + mt * 16 + lo) * 128
                                  + (((ks * 4 + hi) ^ (lo & 7)) << 4));
      #pragma unroll
      for (int nt = 0; nt < 4; ++nt)
        bfr[nt] = *(const bf16x8*)(Bs + (wn * 64 + nt * 16 + lo) * 128
                                   + (((ks * 4 + hi) ^ (lo & 7)) << 4));
      #pragma unroll
      for (int mt = 0; mt < 4; ++mt)
        #pragma unroll
        for (int nt = 0; nt < 4; ++nt)
          acc[mt][nt] = __builtin_amdgcn_mfma_f32_16x16x32_bf16(
              af[mt], bfr[nt], acc[mt][nt], 0, 0, 0);
    }
    __syncthreads();
  }

  const int nn = n0 + wn * 64;
  float bp[4];
  #pragma unroll
  for (int nt = 0; nt < 4; ++nt) bp[nt] = bias[nn + nt * 16 + lo];
  #pragma unroll
  for (int mt = 0; mt < 4; ++mt)
    #pragma unroll
    for (int nt = 0; nt < 4; ++nt)
      #pragma unroll
      for (int reg = 0; reg < 4; ++reg) {
        const int m = m0 + wm * 64 + mt * 16 + hi * 4 + reg;
        out[(size_t)m * CDIM + nn + nt * 16 + lo] = acc[mt][nt][reg] + bp[nt];
      }
}

// ---------------------------------------------------------------------------
extern "C" void kernel_launch(void* const* d_in, const int* in_sizes, int n_in,
                              void* d_out, int out_size, void* d_ws, size_t ws_size,
                              hipStream_t stream) {
  const float* x      = (const float*)d_in[0];
  const float* qkv_w  = (const float*)d_in[1];
  const float* qkv_b  = (const float*)d_in[2];
  const float* proj_w = (const float*)d_in[3];
  const float* proj_b = (const float*)d_in[4];
  const float* cosT   = (const float*)d_in[5];
  const float* sinT   = (const float*)d_in[6];
  float* out = (float*)d_out;

  // ws layout (u16): qb 8MB | kb 8MB | vt 8MB | wb 1.5MB | pwb 0.5MB
  unsigned short* qb  = (unsigned short*)d_ws;
  unsigned short* kb  = qb + (size_t)BDIM * HDIM * LDIM * DDIM;
  unsigned short* vt  = kb + (size_t)BDIM * HDIM * LDIM * DDIM;
  unsigned short* wb  = vt + (size_t)BDIM * HDIM * LDIM * DDIM;
  unsigned short* pwb = wb + (size_t)3 * CDIM * CDIM;

  // 0) fp32 -> bf16 weight conversions (x is converted inside qkv staging)
  convert_kernel<<<dim3(512), 256, 0, stream>>>(qkv_w, proj_w, wb, pwb);
  // 1) QKV GEMM (bf16 MFMA, fp32-x fused convert) + fused RoPE + scatter
  qkv_gemm_kernel<<<dim3(12, 64), 256, 0, stream>>>(x, wb, qkv_b, cosT, sinT,
                                                    qb, kb, vt);
  // 2) bf16 MFMA flash attention (8 waves = 4 q-groups x 2 KV-halves)
  attn_kernel<<<dim3(16, 32), 512, 0, stream>>>(qb, kb, vt);
  // 3) output projection (bf16 MFMA, fp32 out)
  proj_gemm_kernel<<<dim3(4, 64), 256, 0, stream>>>(qb, pwb, proj_b, out);
}

// Round 9
// 97.285 us; speedup vs baseline: 1.2059x; 1.1072x over previous
//
#include <hip/hip_runtime.h>

// Problem constants (B=4, L=2048, C=512, H=8, D=64)
#define CDIM 512
#define LDIM 2048
#define BDIM 4
#define HDIM 8
#define DDIM 64

typedef __attribute__((ext_vector_type(8))) short bf16x8;
typedef __attribute__((ext_vector_type(4))) float f32x4;
typedef __attribute__((ext_vector_type(2))) float f32x2;
typedef __attribute__((ext_vector_type(8))) unsigned short ushort8;

static __device__ __forceinline__ unsigned short f2bf(float f) {
  unsigned u = __float_as_uint(f);
  return (unsigned short)((u + 0x7FFFu + ((u >> 16) & 1u)) >> 16);
}

// ---------------------------------------------------------------------------
// Kernel 0: fp32 -> bf16 convert of x (4194304), qkv_w (786432), proj_w
// (262144). 8 floats/thread, exact grid (5242880/8/256 = 2560 blocks).
// (x conversion restored: async gload_lds staging in qkv beats fused convert
//  by ~12 us -- round 5<->6 ledger.)
// ---------------------------------------------------------------------------
__global__ __launch_bounds__(256) void convert_kernel(
    const float* __restrict__ x, const float* __restrict__ qw,
    const float* __restrict__ pw, unsigned short* __restrict__ xb,
    unsigned short* __restrict__ wb, unsigned short* __restrict__ pwb) {
  const size_t i = ((size_t)blockIdx.x * 256 + threadIdx.x) * 8;
  const float* src; unsigned short* dst; size_t off;
  if (i < 4194304) { src = x;  dst = xb;  off = i; }
  else if (i < 4980736) { src = qw; dst = wb;  off = i - 4194304; }
  else { src = pw; dst = pwb; off = i - 4980736; }
  const float4 a = *(const float4*)(src + off);
  const float4 b = *(const float4*)(src + off + 4);
  ushort8 h;
  h[0] = f2bf(a.x); h[1] = f2bf(a.y); h[2] = f2bf(a.z); h[3] = f2bf(a.w);
  h[4] = f2bf(b.x); h[5] = f2bf(b.y); h[6] = f2bf(b.z); h[7] = f2bf(b.w);
  *(ushort8*)(dst + off) = h;
}

// ---------------------------------------------------------------------------
// Kernel 1: qkv = x @ qkv_w^T + b via bf16 MFMA, fused RoPE epilogue.
// Round-5 structure: both A (bf16 x) and B staged via global_load_lds(16B)
// with pre-swizzled source. 128x128 tile, BK=64, 4 waves.
// ---------------------------------------------------------------------------
__global__ __launch_bounds__(256) void qkv_gemm_kernel(
    const unsigned short* __restrict__ xb, const unsigned short* __restrict__ wb,
    const float* __restrict__ bias, const float* __restrict__ cosT,
    const float* __restrict__ sinT, unsigned short* __restrict__ qb,
    unsigned short* __restrict__ kb, unsigned short* __restrict__ vt) {
  __shared__ char As[16384];
  __shared__ char Bs[16384];
  const int t  = threadIdx.x;
  const int w  = t >> 6, lane = t & 63;
  const int lo = lane & 15, hi = lane >> 4;
  const int wm = w >> 1, wn = w & 1;
  const int m0 = blockIdx.y * 128, n0 = blockIdx.x * 128;

  f32x4 acc[4][4];
  #pragma unroll
  for (int mt = 0; mt < 4; ++mt)
    #pragma unroll
    for (int nt = 0; nt < 4; ++nt) acc[mt][nt] = (f32x4){0.f, 0.f, 0.f, 0.f};

  const int srow   = t >> 3;                         // 0..31 row within slot
  const int schunk = ((t & 7) ^ (srow & 7)) << 4;    // pre-swizzled src byte
  const char* Ag = (const char*)xb;
  const char* Bg = (const char*)wb;

  for (int kt = 0; kt < CDIM; kt += 64) {
    #pragma unroll
    for (int s = 0; s < 4; ++s) {
      const int r = s * 32 + srow;
      __builtin_amdgcn_global_load_lds(
          (const __attribute__((address_space(1))) unsigned int*)
              (Ag + (size_t)(m0 + r) * 1024 + kt * 2 + schunk),
          (__attribute__((address_space(3))) unsigned int*)(As + s * 4096 + w * 1024),
          16, 0, 0);
      __builtin_amdgcn_global_load_lds(
          (const __attribute__((address_space(1))) unsigned int*)
              (Bg + (size_t)(n0 + r) * 1024 + kt * 2 + schunk),
          (__attribute__((address_space(3))) unsigned int*)(Bs + s * 4096 + w * 1024),
          16, 0, 0);
    }
    __syncthreads();
    #pragma unroll
    for (int ks = 0; ks < 2; ++ks) {
      bf16x8 af[4], bfr[4];
      #pragma unroll
      for (int mt = 0; mt < 4; ++mt)
        af[mt] = *(const bf16x8*)(As + (wm * 64 + mt * 16 + lo) * 128
                                  + (((ks * 4 + hi) ^ (lo & 7)) << 4));
      #pragma unroll
      for (int nt = 0; nt < 4; ++nt)
        bfr[nt] = *(const bf16x8*)(Bs + (wn * 64 + nt * 16 + lo) * 128
                                   + (((ks * 4 + hi) ^ (lo & 7)) << 4));
      #pragma unroll
      for (int mt = 0; mt < 4; ++mt)
        #pragma unroll
        for (int nt = 0; nt < 4; ++nt)
          acc[mt][nt] = __builtin_amdgcn_mfma_f32_16x16x32_bf16(
              af[mt], bfr[nt], acc[mt][nt], 0, 0, 0);
    }
    __syncthreads();
  }

  const int nbase = n0 + wn * 64;
  const int typ   = nbase >> 9;
  const int hh    = (nbase >> 6) & 7;
  const int bb    = m0 >> 11;
  const int lbase = (m0 & 2047) + wm * 64;

  float bq[4];
  #pragma unroll
  for (int nt = 0; nt < 4; ++nt) bq[nt] = bias[nbase + nt * 16 + lo];
  #pragma unroll
  for (int mt = 0; mt < 4; ++mt)
    #pragma unroll
    for (int nt = 0; nt < 4; ++nt)
      #pragma unroll
      for (int reg = 0; reg < 4; ++reg) acc[mt][nt][reg] += bq[nt];

  if (typ == 2) {
    unsigned short* vbase = vt + (size_t)(bb * HDIM + hh) * DDIM * LDIM;
    #pragma unroll
    for (int mt = 0; mt < 4; ++mt)
      #pragma unroll
      for (int nt = 0; nt < 4; ++nt) {
        const int d = nt * 16 + lo;
        #pragma unroll
        for (int reg = 0; reg < 4; ++reg) {
          const int l = lbase + mt * 16 + hi * 4 + reg;
          vbase[(size_t)d * LDIM + l] = f2bf(acc[mt][nt][reg]);
        }
      }
  } else {
    unsigned short* dstb = (typ ? kb : qb) + (size_t)(bb * HDIM + hh) * LDIM * DDIM;
    #pragma unroll
    for (int mt = 0; mt < 4; ++mt)
      #pragma unroll
      for (int nt = 0; nt < 4; ++nt) {
        const int d   = nt * 16 + lo;
        const float sgn = (nt & 2) ? 1.f : -1.f;
        #pragma unroll
        for (int reg = 0; reg < 4; ++reg) {
          const int l = lbase + mt * 16 + hi * 4 + reg;
          const float c = cosT[l * 64 + d], s = sinT[l * 64 + d];
          const float v = acc[mt][nt][reg] * c + sgn * acc[mt][nt ^ 2][reg] * s;
          dstb[(size_t)l * DDIM + d] = f2bf(v);
        }
      }
  }
}

// ---------------------------------------------------------------------------
// Kernel 2: bf16 MFMA flash attention, KV-split (round-8 structure).
// Change: V swizzle fixed. V rows are 64B; old chunk = hi ^ (d&3) gave even-d
// lanes only 2 slots -> 4-way conflicts (4.45M). New chunk = hi ^ ((d>>1)&3)
// spreads 8 same-parity lanes over 4 slots -> 2-way (free).
// ---------------------------------------------------------------------------
#define CLOG2 0.18033688f          /* 0.125 * log2(e) */

__global__ __launch_bounds__(512, 4) void attn_kernel(
    unsigned short* __restrict__ qb, const unsigned short* __restrict__ kb,
    const unsigned short* __restrict__ vt) {
  __shared__ char Lds[65536];
  const int t    = threadIdx.x;
  const int w    = t >> 6, lane = t & 63;
  const int lo   = lane & 15, hi = lane >> 4;
  const int wq   = w & 3, half = w >> 2;
  const int bh   = blockIdx.y;
  const int q0   = blockIdx.x * 128 + wq * 32;
  const int kb0  = half * 1024;

  const char* Kb = (const char*)kb + (size_t)bh * (LDIM * DDIM * 2);
  const char* Vb = (const char*)vt + (size_t)bh * (LDIM * DDIM * 2);
  unsigned short* Qb = qb + (size_t)bh * (LDIM * DDIM);

  bf16x8 qf[2][2];
  #pragma unroll
  for (int g = 0; g < 2; ++g)
    #pragma unroll
    for (int kd = 0; kd < 2; ++kd)
      qf[g][kd] = *(const bf16x8*)((const char*)(Qb + (size_t)(q0 + g * 16 + lo) * DDIM)
                                   + kd * 64 + hi * 16);

  f32x4 o[2][4];
  float mrun[2] = {0.f, 0.f}, mc[2] = {0.f, 0.f}, lpart[2] = {0.f, 0.f};
  #pragma unroll
  for (int g = 0; g < 2; ++g)
    #pragma unroll
    for (int r = 0; r < 4; ++r) o[g][r] = (f32x4){0.f, 0.f, 0.f, 0.f};

  const int krow = wq * 8 + (lane >> 3);
  const int kch  = ((lane & 7) ^ (krow & 7)) << 4;
  const int vrow = wq * 16 + (lane >> 2);
  const int vch  = ((lane & 3) ^ ((vrow >> 1) & 3)) << 4;   // FIXED swizzle

  auto stage = [&](int tile, int buf) {
    __builtin_amdgcn_global_load_lds(
        (const __attribute__((address_space(1))) unsigned int*)
            (Kb + (size_t)(kb0 + tile * 32 + krow) * 128 + kch),
        (__attribute__((address_space(3))) unsigned int*)
            (Lds + (half * 2 + buf) * 4096 + wq * 1024),
        16, 0, 0);
    __builtin_amdgcn_global_load_lds(
        (const __attribute__((address_space(1))) unsigned int*)
            (Vb + (size_t)vrow * (LDIM * 2) + (size_t)(kb0 + tile * 32) * 2 + vch),
        (__attribute__((address_space(3))) unsigned int*)
            (Lds + 16384 + (half * 2 + buf) * 4096 + wq * 1024),
        16, 0, 0);
  };

  stage(0, 0);

  char* Pwb = Lds + 32768 + w * 4096;

  for (int kt = 0; kt < 32; ++kt) {
    const int cur = kt & 1;
    const int nk  = kt < 31 ? kt + 1 : 31;
    stage(nk, cur ^ 1);
    asm volatile("s_waitcnt vmcnt(2)");
    __builtin_amdgcn_s_barrier();
    __builtin_amdgcn_sched_barrier(0);

    const char* Kl = Lds + (half * 2 + cur) * 4096;
    const char* Vl = Lds + 16384 + (half * 2 + cur) * 4096;

    // ---- S^T = K Q ----
    f32x4 sv[2][2];
    __builtin_amdgcn_s_setprio(1);
    #pragma unroll
    for (int nt = 0; nt < 2; ++nt) {
      sv[0][nt] = (f32x4){0.f, 0.f, 0.f, 0.f};
      sv[1][nt] = (f32x4){0.f, 0.f, 0.f, 0.f};
      const int key = nt * 16 + lo;
      #pragma unroll
      for (int kd = 0; kd < 2; ++kd) {
        const bf16x8 kf = *(const bf16x8*)(Kl + key * 128
                            + (((kd * 4 + hi) ^ (lo & 7)) << 4));
        sv[0][nt] = __builtin_amdgcn_mfma_f32_16x16x32_bf16(kf, qf[0][kd], sv[0][nt], 0, 0, 0);
        sv[1][nt] = __builtin_amdgcn_mfma_f32_16x16x32_bf16(kf, qf[1][kd], sv[1][nt], 0, 0, 0);
      }
    }
    __builtin_amdgcn_s_setprio(0);

    // ---- softmax per group: no max pass; pk_fma + raw v_exp_f32 ----
    #pragma unroll
    for (int g = 0; g < 2; ++g) {
      const float* sflat = (const float*)sv[g];
      const f32x2 cc2 = {CLOG2, CLOG2};
      const f32x2 mm2 = {-mc[g], -mc[g]};
      float pv[8];
      float ps = 0.f;
      #pragma unroll
      for (int i = 0; i < 4; ++i) {
        f32x2 a; a[0] = sflat[2*i]; a[1] = sflat[2*i+1];
        f32x2 xr;
        asm("v_pk_fma_f32 %0, %1, %2, %3" : "=v"(xr) : "v"(a), "v"(cc2), "v"(mm2));
        float p0, p1;
        asm("v_exp_f32 %0, %1" : "=v"(p0) : "v"(xr[0]));
        asm("v_exp_f32 %0, %1" : "=v"(p1) : "v"(xr[1]));
        pv[2*i] = p0; pv[2*i+1] = p1;
        ps += p0; ps += p1;
      }

      if (__builtin_expect((bool)__ballot(ps > 65536.f), 0)) {
        float mx = -1e30f;
        #pragma unroll
        for (int i = 0; i < 8; ++i) mx = fmaxf(mx, sflat[i]);
        mx = fmaxf(mx, __shfl_xor(mx, 16));
        mx = fmaxf(mx, __shfl_xor(mx, 32));
        const float newm = fmaxf(mrun[g], mx);
        const float al   = exp2f((mrun[g] - newm) * CLOG2);
        lpart[g] *= al;
        #pragma unroll
        for (int r = 0; r < 4; ++r) {
          const float aq = __shfl(al, (hi << 2) + r);
          #pragma unroll
          for (int dt = 0; dt < 4; ++dt) o[g][dt][r] *= aq;
        }
        mrun[g] = newm;
        mc[g]   = newm * CLOG2;
        ps = 0.f;
        #pragma unroll
        for (int i = 0; i < 8; ++i) {
          const float p = exp2f(fmaf(sflat[i], CLOG2, -mc[g]));
          pv[i] = p;
          ps += p;
        }
      }
      lpart[g] += ps;

      #pragma unroll
      for (int nt = 0; nt < 2; ++nt) {
        unsigned w0, w1;
        asm("v_cvt_pk_bf16_f32 %0, %1, %2"
            : "=v"(w0) : "v"(pv[nt*4+0]), "v"(pv[nt*4+1]));
        asm("v_cvt_pk_bf16_f32 %0, %1, %2"
            : "=v"(w1) : "v"(pv[nt*4+2]), "v"(pv[nt*4+3]));
        uint2 d2; d2.x = w0; d2.y = w1;
        *(uint2*)(Pwb + g * 2048 + lo * 128
                  + ((nt * 32 + hi * 8) ^ ((lo & 7) << 4))) = d2;
      }
    }

    // ---- O += P V ----
    __builtin_amdgcn_s_setprio(1);
    {
      const bf16x8 pf0 = *(const bf16x8*)(Pwb + lo * 128
                           + ((hi ^ (lo & 7)) << 4));
      const bf16x8 pf1 = *(const bf16x8*)(Pwb + 2048 + lo * 128
                           + ((hi ^ (lo & 7)) << 4));
      #pragma unroll
      for (int dt = 0; dt < 4; ++dt) {
        const int d = dt * 16 + lo;
        const bf16x8 vf = *(const bf16x8*)(Vl + d * 64
                            + ((hi ^ ((d >> 1) & 3)) << 4));   // FIXED swizzle
        o[0][dt] = __builtin_amdgcn_mfma_f32_16x16x32_bf16(pf0, vf, o[0][dt], 0, 0, 0);
        o[1][dt] = __builtin_amdgcn_mfma_f32_16x16x32_bf16(pf1, vf, o[1][dt], 0, 0, 0);
      }
    }
    __builtin_amdgcn_s_setprio(0);

    __builtin_amdgcn_sched_barrier(0);
    __builtin_amdgcn_s_barrier();
  }

  // ---- epilogue: drain dummy prefetch, merge halves through LDS ----
  asm volatile("s_waitcnt vmcnt(0)");
  __syncthreads();

  float rs[2];
  #pragma unroll
  for (int g = 0; g < 2; ++g) {
    rs[g] = lpart[g];
    rs[g] += __shfl_xor(rs[g], 16);
    rs[g] += __shfl_xor(rs[g], 32);
  }

  if (half == 1) {
    #pragma unroll
    for (int g = 0; g < 2; ++g) {
      #pragma unroll
      for (int dt = 0; dt < 4; ++dt)
        #pragma unroll
        for (int r = 0; r < 4; ++r)
          *(float*)(Lds + wq * 8192
                    + ((g * 16 + hi * 4 + r) * 64 + dt * 16 + lo) * 4) = o[g][dt][r];
      if (hi == 0) {
        *(float*)(Lds + 32768 + wq * 256 + g * 64 + lo * 4)       = rs[g];
        *(float*)(Lds + 32768 + wq * 256 + 128 + g * 64 + lo * 4) = mrun[g];
      }
    }
  }
  __syncthreads();
  if (half == 0) {
    #pragma unroll
    for (int g = 0; g < 2; ++g)
      #pragma unroll
      for (int r = 0; r < 4; ++r) {
        const int qrow = hi * 4 + r;
        const float m_a = __shfl(mrun[g], qrow);
        const float l_a = __shfl(rs[g], qrow);
        const float l_b = *(const float*)(Lds + 32768 + wq * 256 + g * 64 + qrow * 4);
        const float m_b = *(const float*)(Lds + 32768 + wq * 256 + 128 + g * 64 + qrow * 4);
        const float m  = fmaxf(m_a, m_b);
        const float aa = exp2f((m_a - m) * CLOG2);
        const float ab = exp2f((m_b - m) * CLOG2);
        const float inv = 1.f / (l_a * aa + l_b * ab);
        const int q = q0 + g * 16 + qrow;
        #pragma unroll
        for (int dt = 0; dt < 4; ++dt) {
          const float ob = *(const float*)(Lds + wq * 8192
                            + ((g * 16 + qrow) * 64 + dt * 16 + lo) * 4);
          Qb[(size_t)q * DDIM + dt * 16 + lo] =
              f2bf((o[g][dt][r] * aa + ob * ab) * inv);
        }
      }
  }
}

// ---------------------------------------------------------------------------
// Kernel 3: out = attn_out @ proj_w^T + b via bf16 MFMA.
// Re-tiled 64(M)x128(N), BK=64: grid (4,128) = 512 blocks -> 2 blocks/CU
// (old (4,64) was 1 block/CU = 1 wave/SIMD, fully exposed barrier drains).
// Waves 2x2, wave tile 32x64, acc 2x4. Same swizzle scheme as qkv.
// ---------------------------------------------------------------------------
__global__ __launch_bounds__(256) void proj_gemm_kernel(
    const unsigned short* __restrict__ ab, const unsigned short* __restrict__ pwb,
    const float* __restrict__ bias, float* __restrict__ out) {
  __shared__ char As[8192];     // 64 rows x 128B
  __shared__ char Bs[16384];    // 128 rows x 128B
  const int t  = threadIdx.x;
  const int w  = t >> 6, lane = t & 63;
  const int lo = lane & 15, hi = lane >> 4;
  const int wm = w >> 1, wn = w & 1;
  const int m0 = blockIdx.y * 64, n0 = blockIdx.x * 128;

  f32x4 acc[2][4];
  #pragma unroll
  for (int mt = 0; mt < 2; ++mt)
    #pragma unroll
    for (int nt = 0; nt < 4; ++nt) acc[mt][nt] = (f32x4){0.f, 0.f, 0.f, 0.f};

  const int srow   = t >> 3;
  const int schunk = ((t & 7) ^ (srow & 7)) << 4;
  const char* Ag = (const char*)ab;
  const char* Bg = (const char*)pwb;

  for (int kt = 0; kt < CDIM; kt += 64) {
    const int hh = kt >> 6;
    #pragma unroll
    for (int s = 0; s < 2; ++s) {          // A: 64 rows
      const int r = s * 32 + srow;
      const int m = m0 + r;
      const int bb = m >> 11, l = m & 2047;
      __builtin_amdgcn_global_load_lds(
          (const __attribute__((address_space(1))) unsigned int*)
              (Ag + ((size_t)(bb * HDIM + hh) * LDIM + l) * 128 + schunk),
          (__attribute__((address_space(3))) unsigned int*)(As + s * 4096 + w * 1024),
          16, 0, 0);
    }
    #pragma unroll
    for (int s = 0; s < 4; ++s) {          // B: 128 rows
      const int r = s * 32 + srow;
      __builtin_amdgcn_global_load_lds(
          (const __attribute__((address_space(1))) unsigned int*)
              (Bg + (size_t)(n0 + r) * 1024 + kt * 2 + schunk),
          (__attribute__((address_space(3))) unsigned int*)(Bs + s * 4096 + w * 1024),
          16, 0, 0);
    }
    __syncthreads();
    #pragma unroll
    for (int ks = 0; ks < 2; ++ks) {
      bf16x8 af[2], bfr[4];
      #pragma unroll
      for (int mt = 0; mt < 2; ++mt)
        af[mt] = *(const bf16x8*)(As + (wm * 32 + mt * 16 + lo) * 128
                                  + (((ks * 4 + hi) ^ (lo & 7)) << 4));
      #pragma unroll
      for (int nt = 0; nt < 4; ++nt)
        bfr[nt] = *(const bf16x8*)(Bs + (wn * 64 + nt * 16 + lo) * 128
                                   + (((ks * 4 + hi) ^ (lo & 7)) << 4));
      #pragma unroll
      for (int mt = 0; mt < 2; ++mt)
        #pragma unroll
        for (int nt = 0; nt < 4; ++nt)
          acc[mt][nt] = __builtin_amdgcn_mfma_f32_16x16x32_bf16(
              af[mt], bfr[nt], acc[mt][nt], 0, 0, 0);
    }
    __syncthreads();
  }

  const int nn = n0 + wn * 64;
  float bp[4];
  #pragma unroll
  for (int nt = 0; nt < 4; ++nt) bp[nt] = bias[nn + nt * 16 + lo];
  #pragma unroll
  for (int mt = 0; mt < 2; ++mt)
    #pragma unroll
    for (int nt = 0; nt < 4; ++nt)
      #pragma unroll
      for (int reg = 0; reg < 4; ++reg) {
        const int m = m0 + wm * 32 + mt * 16 + hi * 4 + reg;
        out[(size_t)m * CDIM + nn + nt * 16 + lo] = acc[mt][nt][reg] + bp[nt];
      }
}

// ---------------------------------------------------------------------------
extern "C" void kernel_launch(void* const* d_in, const int* in_sizes, int n_in,
                              void* d_out, int out_size, void* d_ws, size_t ws_size,
                              hipStream_t stream) {
  const float* x      = (const float*)d_in[0];
  const float* qkv_w  = (const float*)d_in[1];
  const float* qkv_b  = (const float*)d_in[2];
  const float* proj_w = (const float*)d_in[3];
  const float* proj_b = (const float*)d_in[4];
  const float* cosT   = (const float*)d_in[5];
  const float* sinT   = (const float*)d_in[6];
  float* out = (float*)d_out;

  // ws layout (u16): qb 8MB | kb 8MB | vt 8MB | xb 8MB | wb 1.5MB | pwb 0.5MB
  unsigned short* qb  = (unsigned short*)d_ws;
  unsigned short* kb  = qb + (size_t)BDIM * HDIM * LDIM * DDIM;
  unsigned short* vt  = kb + (size_t)BDIM * HDIM * LDIM * DDIM;
  unsigned short* xb  = vt + (size_t)BDIM * HDIM * LDIM * DDIM;
  unsigned short* wb  = xb + (size_t)BDIM * LDIM * CDIM;
  unsigned short* pwb = wb + (size_t)3 * CDIM * CDIM;

  // 0) fp32 -> bf16 conversions (x + both weights)
  convert_kernel<<<dim3(2560), 256, 0, stream>>>(x, qkv_w, proj_w, xb, wb, pwb);
  // 1) QKV GEMM (bf16 MFMA, async gload_lds staging) + fused RoPE + scatter
  qkv_gemm_kernel<<<dim3(12, 64), 256, 0, stream>>>(xb, wb, qkv_b, cosT, sinT,
                                                    qb, kb, vt);
  // 2) bf16 MFMA flash attention (8 waves = 4 q-groups x 2 KV-halves)
  attn_kernel<<<dim3(16, 32), 512, 0, stream>>>(qb, kb, vt);
  // 3) output projection (64x128 tile, 512 blocks)
  proj_gemm_kernel<<<dim3(4, 128), 256, 0, stream>>>(qb, pwb, proj_b, out);
}